// Round 1
// baseline (1860.032 us; speedup 1.0000x reference)
//
#include <hip/hip_runtime.h>
#include <math.h>

#define D 256
#define HEADS 8
#define DH 32
#define INTER 50
#define INTRA 20
#define BSZ 256
#define CANDN 2048
#define ROWS (BSZ*INTER)   // 12800

// ---------------- intra-session attention + sum-pool (+PE, +u_short) ------
__global__ __launch_bounds__(256) void intra_k(
    const float* __restrict__ item_emb, const int* __restrict__ sess,
    float* __restrict__ S, float* __restrict__ u_short)
{
    __shared__ float x[INTRA][D+1];
    __shared__ float sc[INTRA][INTRA+1];
    __shared__ float wsum[INTRA];
    __shared__ int ids[INTRA];
    int n = blockIdx.x;
    int t = threadIdx.x;
    if (t < INTRA) ids[t] = sess[n*INTRA + t];
    __syncthreads();
    for (int i = 0; i < INTRA; ++i) {
        int id = ids[i];
        x[i][t] = (id == 0) ? 0.f : item_emb[(size_t)id*D + t];
    }
    __syncthreads();
    for (int e = t; e < INTRA*INTRA; e += 256) {
        int q = e / INTRA, k = e % INTRA;
        float dot = 0.f;
        #pragma unroll 8
        for (int c = 0; c < D; ++c) dot += x[q][c]*x[k][c];
        sc[q][k] = (ids[k] != 0) ? dot * (1.0f/16.0f) : -1e9f;
    }
    __syncthreads();
    if (t < INTRA) {
        float m = sc[t][0];
        for (int k = 1; k < INTRA; ++k) m = fmaxf(m, sc[t][k]);
        float s = 0.f;
        for (int k = 0; k < INTRA; ++k) { float e_ = expf(sc[t][k]-m); sc[t][k]=e_; s+=e_; }
        float inv = 1.f/s;
        for (int k = 0; k < INTRA; ++k) sc[t][k] *= inv;
    }
    __syncthreads();
    if (t < INTRA) {
        float s = 0.f;
        for (int q = 0; q < INTRA; ++q) s += sc[q][t];
        wsum[t] = s;
    }
    __syncthreads();
    float v = 0.f;
    #pragma unroll
    for (int k = 0; k < INTRA; ++k) v += wsum[k]*x[k][t];
    int b = n / INTER, srow = n % INTER;
    if (srow == INTER-1) u_short[b*D + t] = v;
    // positional encoding: col 2i -> sin(pos*div_i), col 2i+1 -> cos(pos*div_i)
    int i2 = (t >> 1) * 2;
    float div = expf((float)i2 * (-9.210340371976184f / 256.0f)); // -ln(10000)/d
    float ang = (float)srow * div;
    float pe = (t & 1) ? cosf(ang) : sinf(ang);
    S[(size_t)n*D + t] = v + pe;
}

// ---------------- layernorm (ddof=1) one block per row --------------------
__device__ __forceinline__ float block_sum256(float v, float* red) {
    #pragma unroll
    for (int off = 32; off > 0; off >>= 1) v += __shfl_xor(v, off, 64);
    int wave = threadIdx.x >> 6, lane = threadIdx.x & 63;
    if (lane == 0) red[wave] = v;
    __syncthreads();
    float tot = red[0]+red[1]+red[2]+red[3];
    __syncthreads();
    return tot;
}

__global__ __launch_bounds__(256) void ln_k(const float* __restrict__ X,
    const float* __restrict__ g, const float* __restrict__ b,
    float* __restrict__ Y)
{
    __shared__ float red[4];
    size_t row = blockIdx.x;
    int t = threadIdx.x;
    float x = X[row*D + t];
    float mean = block_sum256(x, red) * (1.f/256.f);
    float d0 = x - mean;
    float var = block_sum256(d0*d0, red) * (1.f/255.f);   // ddof=1
    float stdv = sqrtf(var);
    Y[row*D + t] = g[t]*d0/(stdv+1e-6f) + b[t];
}

// ---------------- generic fp32 GEMM: C = [C +] relu?(A@B + bias) ----------
#define GBM 64
#define GBN 64
#define GBK 16
__global__ __launch_bounds__(256) void gemm_k(
    const float* __restrict__ A, int lda,
    const float* __restrict__ Bw, int ldb,
    const float* __restrict__ bias,
    float* __restrict__ C, int ldc,
    int K, int flags)   // flags bit0: add-to-C, bit1: relu
{
    __shared__ float As[GBK][GBM+1];
    __shared__ float Bs[GBK][GBN+1];
    int tid = threadIdx.x;
    int tx = tid & 15, ty = tid >> 4;
    int bm = blockIdx.y * GBM, bn = blockIdx.x * GBN;
    float acc[4][4] = {};
    int am = tid >> 2, ak = (tid & 3) * 4;
    int bk = tid >> 4, bnn = (tid & 15) * 4;
    for (int k0 = 0; k0 < K; k0 += GBK) {
        float4 av = *(const float4*)(A + (size_t)(bm + am)*lda + k0 + ak);
        As[ak+0][am]=av.x; As[ak+1][am]=av.y; As[ak+2][am]=av.z; As[ak+3][am]=av.w;
        float4 bv = *(const float4*)(Bw + (size_t)(k0 + bk)*ldb + bn + bnn);
        Bs[bk][bnn+0]=bv.x; Bs[bk][bnn+1]=bv.y; Bs[bk][bnn+2]=bv.z; Bs[bk][bnn+3]=bv.w;
        __syncthreads();
        #pragma unroll
        for (int kk = 0; kk < GBK; ++kk) {
            float a0=As[kk][ty*4+0],a1=As[kk][ty*4+1],a2=As[kk][ty*4+2],a3=As[kk][ty*4+3];
            float b0=Bs[kk][tx*4+0],b1=Bs[kk][tx*4+1],b2=Bs[kk][tx*4+2],b3=Bs[kk][tx*4+3];
            acc[0][0]+=a0*b0; acc[0][1]+=a0*b1; acc[0][2]+=a0*b2; acc[0][3]+=a0*b3;
            acc[1][0]+=a1*b0; acc[1][1]+=a1*b1; acc[1][2]+=a1*b2; acc[1][3]+=a1*b3;
            acc[2][0]+=a2*b0; acc[2][1]+=a2*b1; acc[2][2]+=a2*b2; acc[2][3]+=a2*b3;
            acc[3][0]+=a3*b0; acc[3][1]+=a3*b1; acc[3][2]+=a3*b2; acc[3][3]+=a3*b3;
        }
        __syncthreads();
    }
    #pragma unroll
    for (int i = 0; i < 4; ++i) {
        size_t row = bm + ty*4 + i;
        #pragma unroll
        for (int j = 0; j < 4; ++j) {
            int col = bn + tx*4 + j;
            float v_ = acc[i][j];
            if (bias) v_ += bias[col];
            if (flags & 2) v_ = fmaxf(v_, 0.f);
            if (flags & 1) v_ += C[row*ldc + col];
            C[row*ldc + col] = v_;
        }
    }
}

// ---------------- inter-session MHA (one block per (b,h)) -----------------
__global__ __launch_bounds__(256) void att_k(
    const float* __restrict__ Q, const float* __restrict__ K,
    const float* __restrict__ V, const int* __restrict__ sess,
    float* __restrict__ O)
{
    __shared__ float qs[INTER][DH+1], ks[INTER][DH+1], vs[INTER][DH+1];
    __shared__ float p[INTER][INTER+1];
    __shared__ float msk[INTER];
    int b = blockIdx.x >> 3, h = blockIdx.x & 7;
    int t = threadIdx.x;
    for (int idx = t; idx < INTER*DH; idx += 256) {
        int l = idx / DH, e = idx % DH;
        size_t off = ((size_t)(b*INTER + l))*D + h*DH + e;
        qs[l][e] = Q[off]; ks[l][e] = K[off]; vs[l][e] = V[off];
    }
    if (t < INTER) msk[t] = (sess[(b*INTER + t)*INTRA] != 0) ? 1.f : 0.f;
    __syncthreads();
    for (int idx = t; idx < INTER*INTER; idx += 256) {
        int i = idx / INTER, j = idx % INTER;
        float dot = 0.f;
        #pragma unroll
        for (int e = 0; e < DH; ++e) dot += qs[i][e]*ks[j][e];
        p[i][j] = (msk[j] != 0.f) ? dot * 0.17677669529663687f : -1e9f;
    }
    __syncthreads();
    if (t < INTER) {
        float m = p[t][0];
        for (int j = 1; j < INTER; ++j) m = fmaxf(m, p[t][j]);
        float s = 0.f;
        for (int j = 0; j < INTER; ++j) { float e_ = expf(p[t][j]-m); p[t][j]=e_; s+=e_; }
        float inv = 1.f/s;
        for (int j = 0; j < INTER; ++j) p[t][j] *= inv;
    }
    __syncthreads();
    for (int idx = t; idx < INTER*DH; idx += 256) {
        int i = idx / DH, e = idx % DH;
        float s = 0.f;
        #pragma unroll 10
        for (int j = 0; j < INTER; ++j) s += p[i][j]*vs[j][e];
        O[((size_t)(b*INTER + i))*D + h*DH + e] = s;
    }
}

// ---------------- u_long = sum_l LN_fn(S) + user_emb ----------------------
__global__ __launch_bounds__(256) void ulong_k(const float* __restrict__ S1,
    const float* __restrict__ user_emb, const int* __restrict__ us,
    float* __restrict__ u_long)
{
    int b = blockIdx.x, t = threadIdx.x;
    float s = 0.f;
    #pragma unroll 10
    for (int l = 0; l < INTER; ++l) s += S1[((size_t)(b*INTER+l))*D + t];
    int id = us[b];
    float ue = (id == 0) ? 0.f : user_emb[(size_t)id*D + t];
    u_long[b*D + t] = s + ue;
}

// ---------------- gate + fused user repr ----------------------------------
__global__ __launch_bounds__(256) void gate_k(
    const float* __restrict__ u_long, const float* __restrict__ u_short,
    const float* __restrict__ time_emb, const int* __restrict__ tdlt,
    const float* __restrict__ Wl, const float* __restrict__ Ws,
    const float* __restrict__ Wt, const float* __restrict__ gb,
    float* __restrict__ U)
{
    __shared__ float ul[D], ush[D], te[D];
    int b = blockIdx.x, t = threadIdx.x;
    ul[t]  = u_long[b*D + t];
    ush[t] = u_short[b*D + t];
    te[t]  = time_emb[(size_t)tdlt[b]*D + t];
    __syncthreads();
    float acc = gb[t];
    for (int k = 0; k < D; ++k)
        acc += ul[k]*Wl[k*D + t] + ush[k]*Ws[k*D + t] + te[k]*Wt[k*D + t];
    float tg = 1.f/(1.f + expf(-acc));
    U[b*D + t] = tg*ush[t] + (1.f - tg)*ul[t];
}

// ---------------- candidate scoring: one wave per candidate ---------------
__global__ __launch_bounds__(256) void out_k(
    const float* __restrict__ item_emb, const int* __restrict__ pred,
    const float* __restrict__ U, float* __restrict__ out)
{
    __shared__ float u[D];
    int b = blockIdx.x >> 6;               // 64 blocks per batch row
    int cbase = (blockIdx.x & 63) * 32;    // 32 candidates per block
    int t = threadIdx.x;
    u[t] = U[b*D + t];
    __syncthreads();
    int wave = t >> 6, lane = t & 63;
    float4 uv = *(const float4*)(&u[lane*4]);
    for (int it = 0; it < 8; ++it) {
        int c = cbase + it*4 + wave;
        int id = pred[b*CANDN + c];
        float p;
        if (id == 0) { p = 0.f; }
        else {
            const float* row = item_emb + (size_t)id * D;
            float4 rv = *(const float4*)(row + lane*4);
            p = rv.x*uv.x + rv.y*uv.y + rv.z*uv.z + rv.w*uv.w;
        }
        #pragma unroll
        for (int off = 32; off > 0; off >>= 1) p += __shfl_down(p, off, 64);
        if (lane == 0) out[b*CANDN + c] = p;
    }
}

// ---------------------------------------------------------------------------
static inline void gemm(hipStream_t st, const float* A, int lda,
                        const float* Bw, int ldb, const float* bias,
                        float* C, int ldc, int M, int N, int K, int flags) {
    dim3 g(N/GBN, M/GBM);
    gemm_k<<<g, 256, 0, st>>>(A, lda, Bw, ldb, bias, C, ldc, K, flags);
}

extern "C" void kernel_launch(void* const* d_in, const int* in_sizes, int n_in,
                              void* d_out, int out_size, void* d_ws, size_t ws_size,
                              hipStream_t stream)
{
    const float* item_emb = (const float*)d_in[0];
    const float* user_emb = (const float*)d_in[1];
    const float* time_emb = (const float*)d_in[2];
    const float* Wq = (const float*)d_in[3];  const float* bq = (const float*)d_in[4];
    const float* Wk = (const float*)d_in[5];  const float* bk = (const float*)d_in[6];
    const float* Wv = (const float*)d_in[7];  const float* bv = (const float*)d_in[8];
    const float* Wo = (const float*)d_in[9];  const float* bo = (const float*)d_in[10];
    const float* ln1_g = (const float*)d_in[11]; const float* ln1_b = (const float*)d_in[12];
    const float* W1 = (const float*)d_in[13]; const float* b1 = (const float*)d_in[14];
    const float* W2 = (const float*)d_in[15]; const float* b2 = (const float*)d_in[16];
    const float* ln2_g = (const float*)d_in[17]; const float* ln2_b = (const float*)d_in[18];
    const float* fn_g = (const float*)d_in[19]; const float* fn_b = (const float*)d_in[20];
    const float* gWl = (const float*)d_in[21]; const float* gWs = (const float*)d_in[22];
    const float* gWt = (const float*)d_in[23]; const float* gbias = (const float*)d_in[24];
    const int* us   = (const int*)d_in[25];
    const int* sess = (const int*)d_in[26];
    const int* tdlt = (const int*)d_in[27];
    const int* pred = (const int*)d_in[28];
    float* out = (float*)d_out;

    float* ws = (float*)d_ws;
    const size_t NR = (size_t)ROWS * D;    // 3,276,800 floats
    float* S  = ws;                        // (12800,256)
    float* Y  = S + NR;                    // (12800,256)
    float* Qb = Y + NR;                    // (12800,256) -- Qb..Kb also used as (12800,512) FF half
    float* Kb = Qb + NR;
    float* Vb = Kb + NR;
    float* u_short = Vb + NR;              // (256,256)
    float* u_long  = u_short + BSZ*D;      // (256,256)
    float* Ub      = u_long + BSZ*D;       // (256,256)
    // total: 5*NR + 3*65536 floats = ~66.3 MB

    // 1. gather + intra-session attention + sum pool (+PE into S, u_short)
    intra_k<<<ROWS, 256, 0, stream>>>(item_emb, sess, S, u_short);

    // 2. two transformer blocks
    for (int blk = 0; blk < 2; ++blk) {
        ln_k<<<ROWS, 256, 0, stream>>>(S, ln1_g, ln1_b, Y);
        gemm(stream, Y, D, Wq, D, bq, Qb, D, ROWS, D, D, 0);
        gemm(stream, Y, D, Wk, D, bk, Kb, D, ROWS, D, D, 0);
        gemm(stream, Y, D, Wv, D, bv, Vb, D, ROWS, D, D, 0);
        att_k<<<BSZ*HEADS, 256, 0, stream>>>(Qb, Kb, Vb, sess, Y);   // o -> Y
        gemm(stream, Y, D, Wo, D, bo, S, D, ROWS, D, D, 1);          // S += o@Wo+bo
        ln_k<<<ROWS, 256, 0, stream>>>(S, ln2_g, ln2_b, Y);
        // FFN in two 512-wide halves (hidden reuses Qb..Kb as 12800x512)
        gemm(stream, Y, D, W1, 1024, b1, Qb, 512, ROWS, 512, D, 2);          // h_a = relu(...)
        gemm(stream, Qb, 512, W2, D, b2, S, D, ROWS, D, 512, 1);             // S += h_a@W2a + b2
        gemm(stream, Y, D, W1 + 512, 1024, b1 + 512, Qb, 512, ROWS, 512, D, 2); // h_b
        gemm(stream, Qb, 512, W2 + (size_t)512*D, D, nullptr, S, D, ROWS, D, 512, 1); // S += h_b@W2b
    }

    // 3. final norm + u_long
    ln_k<<<ROWS, 256, 0, stream>>>(S, fn_g, fn_b, Y);
    ulong_k<<<BSZ, 256, 0, stream>>>(Y, user_emb, us, u_long);

    // 4. gate -> fused user vector
    gate_k<<<BSZ, 256, 0, stream>>>(u_long, u_short, time_emb, tdlt,
                                    gWl, gWs, gWt, gbias, Ub);

    // 5. candidate scores
    out_k<<<(BSZ*CANDN)/32, 256, 0, stream>>>(item_emb, pred, Ub, out);
}

// Round 2
// 1045.952 us; speedup vs baseline: 1.7783x; 1.7783x over previous
//
#include <hip/hip_runtime.h>
#include <math.h>

#define D 256
#define HEADS 8
#define DH 32
#define INTER 50
#define INTRA 20
#define BSZ 256
#define CANDN 2048
#define ROWS (BSZ*INTER)   // 12800

typedef unsigned short ushort_t;
typedef __attribute__((ext_vector_type(8))) short bf16x8;
typedef __attribute__((ext_vector_type(4))) float f32x4;

__device__ __forceinline__ unsigned short f2b(float f) {
    union { float f; unsigned u; } v; v.f = f;
    unsigned r = v.u + 0x7fffu + ((v.u >> 16) & 1u);
    return (unsigned short)(r >> 16);
}
__device__ __forceinline__ float b2f(unsigned short h) {
    union { unsigned u; float f; } v; v.u = ((unsigned)h) << 16;
    return v.f;
}
__device__ __forceinline__ void gl_lds16(const void* g, void* l) {
    __builtin_amdgcn_global_load_lds(
        (const __attribute__((address_space(1))) unsigned int*)g,
        (__attribute__((address_space(3))) unsigned int*)l, 16, 0, 0);
}

// ---------------- intra-session attention + sum-pool (+PE, +u_short) ------
__global__ __launch_bounds__(256) void intra_k(
    const float* __restrict__ item_emb, const int* __restrict__ sess,
    float* __restrict__ S, float* __restrict__ u_short)
{
    __shared__ float x[INTRA][D+2];          // 258: even stride, f2-aligned
    __shared__ float sc[INTRA][INTRA+1];
    __shared__ float psum[2][100][4];
    __shared__ float wsum[INTRA];
    __shared__ int ids[INTRA];
    int n = blockIdx.x;
    int t = threadIdx.x;
    if (t < INTRA) ids[t] = sess[n*INTRA + t];
    __syncthreads();
    for (int i = 0; i < INTRA; ++i) {
        int id = ids[i];
        x[i][t] = (id == 0) ? 0.f : item_emb[(size_t)id*D + t];
    }
    __syncthreads();
    // scores: 2x2 tiles, K split in 2 halves, float2 LDS reads
    if (t < 200) {
        int tt = t >> 1, half = t & 1;
        int q0 = (tt/10)*2, k0 = (tt%10)*2;
        float s00=0.f,s01=0.f,s10=0.f,s11=0.f;
        int cbeg = half*128, cend = cbeg + 128;
        #pragma unroll 8
        for (int c = cbeg; c < cend; c += 2) {
            float2 qa = *(const float2*)&x[q0  ][c];
            float2 qb = *(const float2*)&x[q0+1][c];
            float2 ka = *(const float2*)&x[k0  ][c];
            float2 kb = *(const float2*)&x[k0+1][c];
            s00 += qa.x*ka.x + qa.y*ka.y;
            s01 += qa.x*kb.x + qa.y*kb.y;
            s10 += qb.x*ka.x + qb.y*ka.y;
            s11 += qb.x*kb.x + qb.y*kb.y;
        }
        psum[half][tt][0]=s00; psum[half][tt][1]=s01;
        psum[half][tt][2]=s10; psum[half][tt][3]=s11;
    }
    __syncthreads();
    if (t < 100) {
        int q0 = (t/10)*2, k0 = (t%10)*2;
        #pragma unroll
        for (int dq = 0; dq < 2; ++dq)
          #pragma unroll
          for (int dk = 0; dk < 2; ++dk) {
            float v_ = psum[0][t][dq*2+dk] + psum[1][t][dq*2+dk];
            sc[q0+dq][k0+dk] = (ids[k0+dk]!=0) ? v_*(1.0f/16.0f) : -1e9f;
          }
    }
    __syncthreads();
    if (t < INTRA) {
        float m = sc[t][0];
        for (int k = 1; k < INTRA; ++k) m = fmaxf(m, sc[t][k]);
        float s = 0.f;
        for (int k = 0; k < INTRA; ++k) { float e_ = expf(sc[t][k]-m); sc[t][k]=e_; s+=e_; }
        float inv = 1.f/s;
        for (int k = 0; k < INTRA; ++k) sc[t][k] *= inv;
    }
    __syncthreads();
    if (t < INTRA) {
        float s = 0.f;
        for (int q = 0; q < INTRA; ++q) s += sc[q][t];
        wsum[t] = s;
    }
    __syncthreads();
    float v = 0.f;
    #pragma unroll
    for (int k = 0; k < INTRA; ++k) v += wsum[k]*x[k][t];
    int b = n / INTER, srow = n % INTER;
    if (srow == INTER-1) u_short[b*D + t] = v;
    int i2 = (t >> 1) * 2;
    float div = expf((float)i2 * (-9.210340371976184f / 256.0f));
    float ang = (float)srow * div;
    float pe = (t & 1) ? cosf(ang) : sinf(ang);
    S[(size_t)n*D + t] = v + pe;
}

// ---------------- layernorm (ddof=1), optional bf16 or fp32 out -----------
__device__ __forceinline__ float block_sum256(float v, float* red) {
    #pragma unroll
    for (int off = 32; off > 0; off >>= 1) v += __shfl_xor(v, off, 64);
    int wave = threadIdx.x >> 6, lane = threadIdx.x & 63;
    if (lane == 0) red[wave] = v;
    __syncthreads();
    float tot = red[0]+red[1]+red[2]+red[3];
    __syncthreads();
    return tot;
}

__global__ __launch_bounds__(256) void ln_k(const float* __restrict__ X,
    const float* __restrict__ g, const float* __restrict__ b,
    unsigned short* __restrict__ Yb, float* __restrict__ Yf)
{
    __shared__ float red[4];
    size_t row = blockIdx.x;
    int t = threadIdx.x;
    float x = X[row*D + t];
    float mean = block_sum256(x, red) * (1.f/256.f);
    float d0 = x - mean;
    float var = block_sum256(d0*d0, red) * (1.f/255.f);   // ddof=1
    float stdv = sqrtf(var);
    float y = g[t]*d0/(stdv+1e-6f) + b[t];
    if (Yb) Yb[row*D + t] = f2b(y);
    else    Yf[row*D + t] = y;
}

// ---------------- bf16 MFMA GEMM: 128x128 tile, BK=32 ---------------------
// C = [Cf +] relu?(A @ BT^T + bias);  A:[M][lda] bf16, BT:[N][K] bf16
#define TM 128
#define TN 128
#define TKK 32
__global__ __launch_bounds__(256) void mgemm_k(
    const unsigned short* __restrict__ A, int lda,
    const unsigned short* __restrict__ BT,
    const float* __restrict__ bias,
    float* __restrict__ Cf, unsigned short* __restrict__ Cb,
    int ldc, int K, int flags)   // bit0: fp32 accum into Cf, bit1: relu
{
    __shared__ __align__(16) unsigned short As[TM*TKK];  // [128][32]
    __shared__ __align__(16) unsigned short Bs[TN*TKK];  // [128][32]
    int tid = threadIdx.x;
    int lane = tid & 63, w = tid >> 6;
    int wrow = (w >> 1) * 64, wcol = (w & 1) * 64;
    int tile_m = blockIdx.y * TM, tile_n = blockIdx.x * TN;
    f32x4 acc[4][4] = {};
    const int r_in_chunk = lane >> 2;           // 16 rows per 1KB chunk
    const int b_in_row = (lane & 3) * 16;       // byte offset within 64B k-row
    const int qoff = (lane >> 4) * 8;
    const int ml = lane & 15;
    for (int k0 = 0; k0 < K; k0 += TKK) {
        #pragma unroll
        for (int i = 0; i < 2; ++i) {
            int c = w*2 + i;
            int row = c*16 + r_in_chunk;
            gl_lds16((const char*)(A + (size_t)(tile_m + row)*lda + k0) + b_in_row,
                     (char*)As + c*1024 + lane*16);
        }
        #pragma unroll
        for (int i = 0; i < 2; ++i) {
            int c = w*2 + i;
            int row = c*16 + r_in_chunk;
            gl_lds16((const char*)(BT + (size_t)(tile_n + row)*K + k0) + b_in_row,
                     (char*)Bs + c*1024 + lane*16);
        }
        __syncthreads();
        bf16x8 af[4], bfr[4];
        #pragma unroll
        for (int mt = 0; mt < 4; ++mt)
            af[mt] = *(const bf16x8*)(As + (wrow + mt*16 + ml)*TKK + qoff);
        #pragma unroll
        for (int nt = 0; nt < 4; ++nt)
            bfr[nt] = *(const bf16x8*)(Bs + (wcol + nt*16 + ml)*TKK + qoff);
        #pragma unroll
        for (int mt = 0; mt < 4; ++mt)
            #pragma unroll
            for (int nt = 0; nt < 4; ++nt)
                acc[mt][nt] = __builtin_amdgcn_mfma_f32_16x16x32_bf16(
                    af[mt], bfr[nt], acc[mt][nt], 0, 0, 0);
        __syncthreads();
    }
    int col_l = lane & 15, rbase = (lane >> 4) * 4;
    #pragma unroll
    for (int mt = 0; mt < 4; ++mt) {
        #pragma unroll
        for (int nt = 0; nt < 4; ++nt) {
            int col = tile_n + wcol + nt*16 + col_l;
            float bs = bias ? bias[col] : 0.f;
            #pragma unroll
            for (int i = 0; i < 4; ++i) {
                size_t row = tile_m + wrow + mt*16 + rbase + i;
                float v_ = acc[mt][nt][i] + bs;
                if (flags & 2) v_ = fmaxf(v_, 0.f);
                if (flags & 1) Cf[row*ldc + col] += v_;
                else           Cb[row*ldc + col] = f2b(v_);
            }
        }
    }
}

// ---------------- weight transpose + fp32->bf16: W[K][N] -> WT[N][K] ------
__global__ __launch_bounds__(256) void wtr_k(const float* __restrict__ W,
    int K, int N, unsigned short* __restrict__ WT)
{
    __shared__ float tile[32][33];
    int n0 = blockIdx.x*32, k0 = blockIdx.y*32;
    int tx = threadIdx.x & 31, ty = threadIdx.x >> 5;   // 32 x 8
    for (int i = ty; i < 32; i += 8)
        tile[i][tx] = W[(size_t)(k0+i)*N + n0 + tx];
    __syncthreads();
    for (int i = ty; i < 32; i += 8)
        WT[(size_t)(n0+i)*K + k0 + tx] = f2b(tile[tx][i]);
}

__global__ void bcat_k(const float* __restrict__ bq, const float* __restrict__ bk,
                       const float* __restrict__ bv, float* __restrict__ o)
{
    int t = threadIdx.x;
    o[t] = bq[t]; o[256+t] = bk[t]; o[512+t] = bv[t];
}

// ---------------- inter-session MHA (one block per (b,h)), bf16 I/O -------
__global__ __launch_bounds__(256) void att_k(
    const unsigned short* __restrict__ QKV, const int* __restrict__ sess,
    unsigned short* __restrict__ O)
{
    __shared__ float qs[INTER][DH+1], ks[INTER][DH+1], vs[INTER][DH+1];
    __shared__ float p[INTER][INTER+1];
    __shared__ float msk[INTER];
    int b = blockIdx.x >> 3, h = blockIdx.x & 7;
    int t = threadIdx.x;
    for (int idx = t; idx < INTER*DH; idx += 256) {
        int l = idx / DH, e = idx % DH;
        size_t off = ((size_t)(b*INTER + l))*768 + h*DH + e;
        qs[l][e] = b2f(QKV[off]);
        ks[l][e] = b2f(QKV[off + 256]);
        vs[l][e] = b2f(QKV[off + 512]);
    }
    if (t < INTER) msk[t] = (sess[(b*INTER + t)*INTRA] != 0) ? 1.f : 0.f;
    __syncthreads();
    for (int idx = t; idx < INTER*INTER; idx += 256) {
        int i = idx / INTER, j = idx % INTER;
        float dot = 0.f;
        #pragma unroll
        for (int e = 0; e < DH; ++e) dot += qs[i][e]*ks[j][e];
        p[i][j] = (msk[j] != 0.f) ? dot * 0.17677669529663687f : -1e9f;
    }
    __syncthreads();
    if (t < INTER) {
        float m = p[t][0];
        for (int j = 1; j < INTER; ++j) m = fmaxf(m, p[t][j]);
        float s = 0.f;
        for (int j = 0; j < INTER; ++j) { float e_ = expf(p[t][j]-m); p[t][j]=e_; s+=e_; }
        float inv = 1.f/s;
        for (int j = 0; j < INTER; ++j) p[t][j] *= inv;
    }
    __syncthreads();
    for (int idx = t; idx < INTER*DH; idx += 256) {
        int i = idx / DH, e = idx % DH;
        float s = 0.f;
        #pragma unroll 10
        for (int j = 0; j < INTER; ++j) s += p[i][j]*vs[j][e];
        O[((size_t)(b*INTER + i))*D + h*DH + e] = f2b(s);
    }
}

// ---------------- u_long = sum_l LN_fn(S) + user_emb ----------------------
__global__ __launch_bounds__(256) void ulong_k(const float* __restrict__ S1,
    const float* __restrict__ user_emb, const int* __restrict__ us,
    float* __restrict__ u_long)
{
    int b = blockIdx.x, t = threadIdx.x;
    float s = 0.f;
    #pragma unroll 10
    for (int l = 0; l < INTER; ++l) s += S1[((size_t)(b*INTER+l))*D + t];
    int id = us[b];
    float ue = (id == 0) ? 0.f : user_emb[(size_t)id*D + t];
    u_long[b*D + t] = s + ue;
}

// ---------------- gate + fused user repr ----------------------------------
__global__ __launch_bounds__(256) void gate_k(
    const float* __restrict__ u_long, const float* __restrict__ u_short,
    const float* __restrict__ time_emb, const int* __restrict__ tdlt,
    const float* __restrict__ Wl, const float* __restrict__ Ws,
    const float* __restrict__ Wt, const float* __restrict__ gb,
    float* __restrict__ U)
{
    __shared__ float ul[D], ush[D], te[D];
    int b = blockIdx.x, t = threadIdx.x;
    ul[t]  = u_long[b*D + t];
    ush[t] = u_short[b*D + t];
    te[t]  = time_emb[(size_t)tdlt[b]*D + t];
    __syncthreads();
    float acc = gb[t];
    for (int k = 0; k < D; ++k)
        acc += ul[k]*Wl[k*D + t] + ush[k]*Ws[k*D + t] + te[k]*Wt[k*D + t];
    float tg = 1.f/(1.f + expf(-acc));
    U[b*D + t] = tg*ush[t] + (1.f - tg)*ul[t];
}

// ---------------- candidate scoring: one wave per candidate ---------------
__global__ __launch_bounds__(256) void out_k(
    const float* __restrict__ item_emb, const int* __restrict__ pred,
    const float* __restrict__ U, float* __restrict__ out)
{
    __shared__ float u[D];
    int b = blockIdx.x >> 6;
    int cbase = (blockIdx.x & 63) * 32;
    int t = threadIdx.x;
    u[t] = U[b*D + t];
    __syncthreads();
    int wave = t >> 6, lane = t & 63;
    float4 uv = *(const float4*)(&u[lane*4]);
    for (int it = 0; it < 8; ++it) {
        int c = cbase + it*4 + wave;
        int id = pred[b*CANDN + c];
        float p;
        if (id == 0) { p = 0.f; }
        else {
            const float* row = item_emb + (size_t)id * D;
            float4 rv = *(const float4*)(row + lane*4);
            p = rv.x*uv.x + rv.y*uv.y + rv.z*uv.z + rv.w*uv.w;
        }
        #pragma unroll
        for (int off = 32; off > 0; off >>= 1) p += __shfl_down(p, off, 64);
        if (lane == 0) out[b*CANDN + c] = p;
    }
}

// ---------------------------------------------------------------------------
extern "C" void kernel_launch(void* const* d_in, const int* in_sizes, int n_in,
                              void* d_out, int out_size, void* d_ws, size_t ws_size,
                              hipStream_t stream)
{
    const float* item_emb = (const float*)d_in[0];
    const float* user_emb = (const float*)d_in[1];
    const float* time_emb = (const float*)d_in[2];
    const float* Wq = (const float*)d_in[3];  const float* bq = (const float*)d_in[4];
    const float* Wk = (const float*)d_in[5];  const float* bk = (const float*)d_in[6];
    const float* Wv = (const float*)d_in[7];  const float* bv = (const float*)d_in[8];
    const float* Wo = (const float*)d_in[9];  const float* bo = (const float*)d_in[10];
    const float* ln1_g = (const float*)d_in[11]; const float* ln1_b = (const float*)d_in[12];
    const float* W1 = (const float*)d_in[13]; const float* b1 = (const float*)d_in[14];
    const float* W2 = (const float*)d_in[15]; const float* b2 = (const float*)d_in[16];
    const float* ln2_g = (const float*)d_in[17]; const float* ln2_b = (const float*)d_in[18];
    const float* fn_g = (const float*)d_in[19]; const float* fn_b = (const float*)d_in[20];
    const float* gWl = (const float*)d_in[21]; const float* gWs = (const float*)d_in[22];
    const float* gWt = (const float*)d_in[23]; const float* gbias = (const float*)d_in[24];
    const int* us   = (const int*)d_in[25];
    const int* sess = (const int*)d_in[26];
    const int* tdlt = (const int*)d_in[27];
    const int* pred = (const int*)d_in[28];
    float* out = (float*)d_out;

    char* ws = (char*)d_ws;
    // fp32 S
    float* S = (float*)ws;                       ws += (size_t)ROWS*D*4;       // 13.1 MB
    // bf16 activations
    unsigned short* Ybf = (unsigned short*)ws;   ws += (size_t)ROWS*D*2;       // 6.55 MB
    unsigned short* QKVb = (unsigned short*)ws;  // overlaid region: max(QKV 19.7MB, H 26.2MB, LNfin fp32 13.1MB)
    unsigned short* Hb = QKVb;
    float* LNf = (float*)QKVb;
    ws += (size_t)ROWS*1024*2;                                                // 26.2 MB
    // bf16 weights
    unsigned short* WqkvT = (unsigned short*)ws; ws += (size_t)768*256*2;
    unsigned short* WoT   = (unsigned short*)ws; ws += (size_t)256*256*2;
    unsigned short* W1T   = (unsigned short*)ws; ws += (size_t)1024*256*2;
    unsigned short* W2T   = (unsigned short*)ws; ws += (size_t)256*1024*2;
    float* bqkv = (float*)ws;                    ws += 768*4;
    float* u_short = (float*)ws;                 ws += BSZ*D*4;
    float* u_long  = (float*)ws;                 ws += BSZ*D*4;
    float* Ufin    = (float*)ws;                 ws += BSZ*D*4;

    // ---- weight prep (every launch; ws is re-poisoned) ----
    wtr_k<<<dim3(8,8),   256, 0, stream>>>(Wq, 256, 256,  WqkvT);
    wtr_k<<<dim3(8,8),   256, 0, stream>>>(Wk, 256, 256,  WqkvT + 256*256);
    wtr_k<<<dim3(8,8),   256, 0, stream>>>(Wv, 256, 256,  WqkvT + 512*256);
    wtr_k<<<dim3(8,8),   256, 0, stream>>>(Wo, 256, 256,  WoT);
    wtr_k<<<dim3(32,8),  256, 0, stream>>>(W1, 256, 1024, W1T);
    wtr_k<<<dim3(8,32),  256, 0, stream>>>(W2, 1024, 256, W2T);
    bcat_k<<<1, 256, 0, stream>>>(bq, bk, bv, bqkv);

    // ---- 1. intra-session attention ----
    intra_k<<<ROWS, 256, 0, stream>>>(item_emb, sess, S, u_short);

    // ---- 2. transformer blocks ----
    for (int blk = 0; blk < 2; ++blk) {
        ln_k<<<ROWS, 256, 0, stream>>>(S, ln1_g, ln1_b, Ybf, nullptr);
        mgemm_k<<<dim3(6,100), 256, 0, stream>>>(Ybf, D, WqkvT, bqkv,
                                                 nullptr, QKVb, 768, 256, 0);
        att_k<<<BSZ*HEADS, 256, 0, stream>>>(QKVb, sess, Ybf);
        mgemm_k<<<dim3(2,100), 256, 0, stream>>>(Ybf, D, WoT, bo,
                                                 S, nullptr, 256, 256, 1);
        ln_k<<<ROWS, 256, 0, stream>>>(S, ln2_g, ln2_b, Ybf, nullptr);
        mgemm_k<<<dim3(8,100), 256, 0, stream>>>(Ybf, D, W1T, b1,
                                                 nullptr, Hb, 1024, 256, 2);
        mgemm_k<<<dim3(2,100), 256, 0, stream>>>(Hb, 1024, W2T, b2,
                                                 S, nullptr, 256, 1024, 1);
    }

    // ---- 3. final LN + u_long ----
    ln_k<<<ROWS, 256, 0, stream>>>(S, fn_g, fn_b, nullptr, LNf);
    ulong_k<<<BSZ, 256, 0, stream>>>(LNf, user_emb, us, u_long);

    // ---- 4. gate ----
    gate_k<<<BSZ, 256, 0, stream>>>(u_long, u_short, time_emb, tdlt,
                                    gWl, gWs, gWt, gbias, Ufin);

    // ---- 5. candidate scores ----
    out_k<<<(BSZ*CANDN)/32, 256, 0, stream>>>(item_emb, pred, Ufin, out);
}

// Round 3
// 883.472 us; speedup vs baseline: 2.1054x; 1.1839x over previous
//
#include <hip/hip_runtime.h>
#include <math.h>

#define D 256
#define HEADS 8
#define DH 32
#define INTER 50
#define INTRA 20
#define BSZ 256
#define CANDN 2048
#define ROWS (BSZ*INTER)   // 12800

typedef unsigned short ushort_t;
typedef __attribute__((ext_vector_type(8))) short bf16x8;
typedef __attribute__((ext_vector_type(4))) float f32x4;

__device__ __forceinline__ unsigned short f2b(float f) {
    union { float f; unsigned u; } v; v.f = f;
    unsigned r = v.u + 0x7fffu + ((v.u >> 16) & 1u);
    return (unsigned short)(r >> 16);
}
__device__ __forceinline__ float b2f(unsigned short h) {
    union { unsigned u; float f; } v; v.u = ((unsigned)h) << 16;
    return v.f;
}
__device__ __forceinline__ void gl_lds16(const void* g, void* l) {
    __builtin_amdgcn_global_load_lds(
        (const __attribute__((address_space(1))) unsigned int*)g,
        (__attribute__((address_space(3))) unsigned int*)l, 16, 0, 0);
}

// ============ intra-session attention via MFMA ============================
// 4 sessions per block, one wave per session.
#define XST 264   // bf16 row stride: 528B = 33*16 (16-aligned rows)
__global__ __launch_bounds__(256) void intra_k(
    const float* __restrict__ item_emb, const int* __restrict__ sess,
    float* __restrict__ S, float* __restrict__ u_short)
{
    __shared__ __align__(16) unsigned short xb[4][32][XST];
    __shared__ float sc[4][20][21];
    __shared__ float wsum[4][20];
    __shared__ int ids[4][INTRA];
    int t = threadIdx.x, w = t >> 6, lane = t & 63;
    int s = blockIdx.x*4 + w;                 // session index
    if (lane < INTRA) ids[w][lane] = sess[s*INTRA + lane];
    __syncthreads();
    int col = lane*4;                         // 0..252
    // gather + fp32->bf16
    for (int r = 0; r < INTRA; ++r) {
        int id = ids[w][r];
        float4 v4;
        if (id) v4 = *(const float4*)(item_emb + (size_t)id*D + col);
        else    v4 = make_float4(0.f,0.f,0.f,0.f);
        ushort4 h; h.x=f2b(v4.x); h.y=f2b(v4.y); h.z=f2b(v4.z); h.w=f2b(v4.w);
        *(ushort4*)&xb[w][r][col] = h;
    }
    {
        ushort4 z = {0,0,0,0};
        for (int r = INTRA; r < 32; ++r) *(ushort4*)&xb[w][r][col] = z;
    }
    __syncthreads();
    // scores = X @ X^T : 2x2 tiles of 16x16, K=256
    int ml = lane & 15, q8 = (lane >> 4) * 8;
    f32x4 acc[2][2] = {};
    for (int k0 = 0; k0 < D; k0 += 32) {
        bf16x8 fr0 = *(const bf16x8*)&xb[w][ml     ][k0 + q8];
        bf16x8 fr1 = *(const bf16x8*)&xb[w][16 + ml][k0 + q8];
        acc[0][0] = __builtin_amdgcn_mfma_f32_16x16x32_bf16(fr0, fr0, acc[0][0], 0,0,0);
        acc[0][1] = __builtin_amdgcn_mfma_f32_16x16x32_bf16(fr0, fr1, acc[0][1], 0,0,0);
        acc[1][0] = __builtin_amdgcn_mfma_f32_16x16x32_bf16(fr1, fr0, acc[1][0], 0,0,0);
        acc[1][1] = __builtin_amdgcn_mfma_f32_16x16x32_bf16(fr1, fr1, acc[1][1], 0,0,0);
    }
    int rb = (lane >> 4) * 4;
    #pragma unroll
    for (int mt = 0; mt < 2; ++mt)
        #pragma unroll
        for (int nt = 0; nt < 2; ++nt)
            #pragma unroll
            for (int i = 0; i < 4; ++i) {
                int row = mt*16 + rb + i, cc = nt*16 + ml;
                if (row < INTRA && cc < INTRA) sc[w][row][cc] = acc[mt][nt][i];
            }
    __syncthreads();
    // softmax rows (per wave, lanes<20), masked + scaled
    if (lane < INTRA) {
        float vrow[INTRA]; float mx = -1e30f;
        #pragma unroll
        for (int k = 0; k < INTRA; ++k) {
            float v_ = (ids[w][k] != 0) ? sc[w][lane][k]*(1.0f/16.0f) : -1e9f;
            vrow[k] = v_; mx = fmaxf(mx, v_);
        }
        float ssum = 0.f;
        #pragma unroll
        for (int k = 0; k < INTRA; ++k) { float e_ = expf(vrow[k]-mx); vrow[k]=e_; ssum+=e_; }
        float inv = 1.f/ssum;
        #pragma unroll
        for (int k = 0; k < INTRA; ++k) sc[w][lane][k] = vrow[k]*inv;
    }
    __syncthreads();
    if (lane < INTRA) {
        float s_ = 0.f;
        #pragma unroll
        for (int q = 0; q < INTRA; ++q) s_ += sc[w][q][lane];
        wsum[w][lane] = s_;
    }
    __syncthreads();
    // pooled = sum_k wsum[k] * x[k][:]
    float4 v = {0.f,0.f,0.f,0.f};
    #pragma unroll
    for (int k = 0; k < INTRA; ++k) {
        float ws_ = wsum[w][k];
        ushort4 h = *(const ushort4*)&xb[w][k][col];
        v.x += ws_*b2f(h.x); v.y += ws_*b2f(h.y);
        v.z += ws_*b2f(h.z); v.w += ws_*b2f(h.w);
    }
    int b = s / INTER, srow = s % INTER;
    if (srow == INTER-1) *(float4*)(u_short + (size_t)b*D + col) = v;
    const float kc = -9.210340371976184f / 256.0f;   // -ln(10000)/d
    float div0 = expf((float)col * kc);
    float div2 = expf((float)(col+2) * kc);
    float4 o;
    o.x = v.x + sinf((float)srow * div0);
    o.y = v.y + cosf((float)srow * div0);
    o.z = v.z + sinf((float)srow * div2);
    o.w = v.w + cosf((float)srow * div2);
    *(float4*)(S + (size_t)s*D + col) = o;
}

// ============ layernorm (ddof=1): wave per row, shuffle-only ==============
__global__ __launch_bounds__(256) void ln4_k(const float* __restrict__ X,
    const float* __restrict__ g, const float* __restrict__ bb,
    unsigned short* __restrict__ Yb, float* __restrict__ Yf)
{
    int w = threadIdx.x >> 6, lane = threadIdx.x & 63;
    size_t row = (size_t)blockIdx.x*4 + w;
    int col = lane*4;
    float4 x = *(const float4*)(X + row*D + col);
    float s_ = x.x + x.y + x.z + x.w;
    #pragma unroll
    for (int off = 32; off > 0; off >>= 1) s_ += __shfl_xor(s_, off, 64);
    float mean = s_ * (1.f/256.f);
    float4 d0; d0.x = x.x-mean; d0.y = x.y-mean; d0.z = x.z-mean; d0.w = x.w-mean;
    float q_ = d0.x*d0.x + d0.y*d0.y + d0.z*d0.z + d0.w*d0.w;
    #pragma unroll
    for (int off = 32; off > 0; off >>= 1) q_ += __shfl_xor(q_, off, 64);
    float inv = 1.f/(sqrtf(q_ * (1.f/255.f)) + 1e-6f);
    float4 g4 = *(const float4*)(g + col), b4 = *(const float4*)(bb + col);
    float4 y;
    y.x = g4.x*d0.x*inv + b4.x; y.y = g4.y*d0.y*inv + b4.y;
    y.z = g4.z*d0.z*inv + b4.z; y.w = g4.w*d0.w*inv + b4.w;
    if (Yb) {
        ushort4 h; h.x=f2b(y.x); h.y=f2b(y.y); h.z=f2b(y.z); h.w=f2b(y.w);
        *(ushort4*)(Yb + row*D + col) = h;
    } else {
        *(float4*)(Yf + row*D + col) = y;
    }
}

// ============ bf16 MFMA GEMM: 128x128 tile, BK=32 (unchanged) =============
#define TM 128
#define TN 128
#define TKK 32
__global__ __launch_bounds__(256) void mgemm_k(
    const unsigned short* __restrict__ A, int lda,
    const unsigned short* __restrict__ BT,
    const float* __restrict__ bias,
    float* __restrict__ Cf, unsigned short* __restrict__ Cb,
    int ldc, int K, int flags)   // bit0: fp32 accum into Cf, bit1: relu
{
    __shared__ __align__(16) unsigned short As[TM*TKK];
    __shared__ __align__(16) unsigned short Bs[TN*TKK];
    int tid = threadIdx.x;
    int lane = tid & 63, w = tid >> 6;
    int wrow = (w >> 1) * 64, wcol = (w & 1) * 64;
    int tile_m = blockIdx.y * TM, tile_n = blockIdx.x * TN;
    f32x4 acc[4][4] = {};
    const int r_in_chunk = lane >> 2;
    const int b_in_row = (lane & 3) * 16;
    const int qoff = (lane >> 4) * 8;
    const int ml = lane & 15;
    for (int k0 = 0; k0 < K; k0 += TKK) {
        #pragma unroll
        for (int i = 0; i < 2; ++i) {
            int c = w*2 + i;
            int row = c*16 + r_in_chunk;
            gl_lds16((const char*)(A + (size_t)(tile_m + row)*lda + k0) + b_in_row,
                     (char*)As + c*1024 + lane*16);
        }
        #pragma unroll
        for (int i = 0; i < 2; ++i) {
            int c = w*2 + i;
            int row = c*16 + r_in_chunk;
            gl_lds16((const char*)(BT + (size_t)(tile_n + row)*K + k0) + b_in_row,
                     (char*)Bs + c*1024 + lane*16);
        }
        __syncthreads();
        bf16x8 af[4], bfr[4];
        #pragma unroll
        for (int mt = 0; mt < 4; ++mt)
            af[mt] = *(const bf16x8*)(As + (wrow + mt*16 + ml)*TKK + qoff);
        #pragma unroll
        for (int nt = 0; nt < 4; ++nt)
            bfr[nt] = *(const bf16x8*)(Bs + (wcol + nt*16 + ml)*TKK + qoff);
        #pragma unroll
        for (int mt = 0; mt < 4; ++mt)
            #pragma unroll
            for (int nt = 0; nt < 4; ++nt)
                acc[mt][nt] = __builtin_amdgcn_mfma_f32_16x16x32_bf16(
                    af[mt], bfr[nt], acc[mt][nt], 0, 0, 0);
        __syncthreads();
    }
    int col_l = lane & 15, rbase = (lane >> 4) * 4;
    #pragma unroll
    for (int mt = 0; mt < 4; ++mt) {
        #pragma unroll
        for (int nt = 0; nt < 4; ++nt) {
            int col = tile_n + wcol + nt*16 + col_l;
            float bs = bias ? bias[col] : 0.f;
            #pragma unroll
            for (int i = 0; i < 4; ++i) {
                size_t row = tile_m + wrow + mt*16 + rbase + i;
                float v_ = acc[mt][nt][i] + bs;
                if (flags & 2) v_ = fmaxf(v_, 0.f);
                if (flags & 1) Cf[row*ldc + col] += v_;
                else           Cb[row*ldc + col] = f2b(v_);
            }
        }
    }
}

// ============ weight transpose + fp32->bf16 ===============================
__global__ __launch_bounds__(256) void wtr_k(const float* __restrict__ W,
    int K, int N, unsigned short* __restrict__ WT)
{
    __shared__ float tile[32][33];
    int n0 = blockIdx.x*32, k0 = blockIdx.y*32;
    int tx = threadIdx.x & 31, ty = threadIdx.x >> 5;
    for (int i = ty; i < 32; i += 8)
        tile[i][tx] = W[(size_t)(k0+i)*N + n0 + tx];
    __syncthreads();
    for (int i = ty; i < 32; i += 8)
        WT[(size_t)(n0+i)*K + k0 + tx] = f2b(tile[tx][i]);
}

__global__ void bcat_k(const float* __restrict__ bq, const float* __restrict__ bk,
                       const float* __restrict__ bv, float* __restrict__ o)
{
    int t = threadIdx.x;
    o[t] = bq[t]; o[256+t] = bk[t]; o[512+t] = bv[t];
}

// ============ inter-session MHA via MFMA: block per (b,h) =================
#define AST 40    // qs/ks stride (80B, 16-aligned)
#define PST 72    // pb / vst stride (144B, 16-aligned)
__global__ __launch_bounds__(256) void att_k(
    const unsigned short* __restrict__ QKV, const int* __restrict__ sess,
    unsigned short* __restrict__ O)
{
    __shared__ __align__(16) unsigned short qs[64][AST];
    __shared__ __align__(16) unsigned short ks[64][AST];
    __shared__ __align__(16) unsigned short vst[32][PST];  // V^T: [n][k]
    __shared__ __align__(16) unsigned short pb[64][PST];   // P bf16: [m][k]
    __shared__ float p[50][52];
    __shared__ float msk[52];
    int b = blockIdx.x >> 3, h = blockIdx.x & 7;
    int t = threadIdx.x, w = t >> 6, lane = t & 63;
    // stage Q,K: 2 arrays x 50 rows x 4 chunks(8 bf16)
    for (int u = t; u < 400; u += 256) {
        int arr = u / 200, rem = u % 200, row = rem >> 2, part = rem & 3;
        const unsigned short* src = QKV + ((size_t)(b*INTER+row))*768 + arr*256 + h*32 + part*8;
        ushort4 a = *(const ushort4*)src, c = *(const ushort4*)(src+4);
        unsigned short* dst = (arr ? ks[row] : qs[row]) + part*8;
        *(ushort4*)dst = a; *(ushort4*)(dst+4) = c;
    }
    // stage V transposed (scalar)
    for (int u = t; u < INTER*32; u += 256) {
        int row = u >> 5, e = u & 31;
        vst[e][row] = QKV[((size_t)(b*INTER+row))*768 + 512 + h*32 + e];
    }
    // zero V^T k-pad (k=50..63)
    for (int u = t; u < 32*14; u += 256) {
        int e = u / 14, k = 50 + (u % 14);
        vst[e][k] = 0;
    }
    // zero P k-pad (k=50..63, all rows)
    for (int u = t; u < 64*14; u += 256) {
        int r = u / 14, k = 50 + (u % 14);
        pb[r][k] = 0;
    }
    if (t < INTER) msk[t] = (sess[(b*INTER + t)*INTRA] != 0) ? 1.f : 0.f;
    __syncthreads();
    // QK^T: wave w = m-tile; K=32 -> one MFMA per 16x16 tile
    int ml = lane & 15, q8 = (lane >> 4) * 8, rb = (lane >> 4) * 4;
    {
        bf16x8 afq = *(const bf16x8*)&qs[w*16 + ml][q8];
        #pragma unroll
        for (int nt = 0; nt < 4; ++nt) {
            bf16x8 bfk = *(const bf16x8*)&ks[nt*16 + ml][q8];
            f32x4 a0 = {};
            a0 = __builtin_amdgcn_mfma_f32_16x16x32_bf16(afq, bfk, a0, 0, 0, 0);
            #pragma unroll
            for (int i = 0; i < 4; ++i) {
                int row = w*16 + rb + i, cc = nt*16 + ml;
                if (row < INTER && cc < INTER)
                    p[row][cc] = (msk[cc] != 0.f) ? a0[i]*0.17677669529663687f : -1e9f;
            }
        }
    }
    __syncthreads();
    // softmax rows 0..49 (wave 0), 3-pass, write bf16 P
    if (t < INTER) {
        float mx = -1e30f;
        for (int k = 0; k < INTER; ++k) mx = fmaxf(mx, p[t][k]);
        float ssum = 0.f;
        for (int k = 0; k < INTER; ++k) { float e_ = expf(p[t][k]-mx); p[t][k] = e_; ssum += e_; }
        float inv = 1.f/ssum;
        for (int k = 0; k < INTER; ++k) pb[t][k] = f2b(p[t][k]*inv);
    }
    __syncthreads();
    // PV: wave w = m-tile, n-tiles 0..1, K=64 (2 k-tiles)
    f32x4 acco[2] = {};
    #pragma unroll
    for (int kt = 0; kt < 2; ++kt) {
        bf16x8 ap = *(const bf16x8*)&pb[w*16 + ml][kt*32 + q8];
        #pragma unroll
        for (int nt = 0; nt < 2; ++nt) {
            bf16x8 bv = *(const bf16x8*)&vst[nt*16 + ml][kt*32 + q8];
            acco[nt] = __builtin_amdgcn_mfma_f32_16x16x32_bf16(ap, bv, acco[nt], 0, 0, 0);
        }
    }
    #pragma unroll
    for (int nt = 0; nt < 2; ++nt)
        #pragma unroll
        for (int i = 0; i < 4; ++i) {
            int row = w*16 + rb + i, cc = nt*16 + ml;
            if (row < INTER)
                O[((size_t)(b*INTER+row))*D + h*DH + cc] = f2b(acco[nt][i]);
        }
}

// ============ u_long = sum_l LN_fn(S) + user_emb ==========================
__global__ __launch_bounds__(256) void ulong_k(const float* __restrict__ S1,
    const float* __restrict__ user_emb, const int* __restrict__ us,
    float* __restrict__ u_long)
{
    int b = blockIdx.x, t = threadIdx.x;
    float s = 0.f;
    #pragma unroll 10
    for (int l = 0; l < INTER; ++l) s += S1[((size_t)(b*INTER+l))*D + t];
    int id = us[b];
    float ue = (id == 0) ? 0.f : user_emb[(size_t)id*D + t];
    u_long[b*D + t] = s + ue;
}

// ============ gate + fused user repr ======================================
__global__ __launch_bounds__(256) void gate_k(
    const float* __restrict__ u_long, const float* __restrict__ u_short,
    const float* __restrict__ time_emb, const int* __restrict__ tdlt,
    const float* __restrict__ Wl, const float* __restrict__ Ws,
    const float* __restrict__ Wt, const float* __restrict__ gb,
    float* __restrict__ U)
{
    __shared__ float ul[D], ush[D], te[D];
    int b = blockIdx.x, t = threadIdx.x;
    ul[t]  = u_long[b*D + t];
    ush[t] = u_short[b*D + t];
    te[t]  = time_emb[(size_t)tdlt[b]*D + t];
    __syncthreads();
    float acc = gb[t];
    for (int k = 0; k < D; ++k)
        acc += ul[k]*Wl[k*D + t] + ush[k]*Ws[k*D + t] + te[k]*Wt[k*D + t];
    float tg = 1.f/(1.f + expf(-acc));
    U[b*D + t] = tg*ush[t] + (1.f - tg)*ul[t];
}

// ============ candidate scoring ===========================================
__global__ __launch_bounds__(256) void out_k(
    const float* __restrict__ item_emb, const int* __restrict__ pred,
    const float* __restrict__ U, float* __restrict__ out)
{
    __shared__ float u[D];
    int b = blockIdx.x >> 6;
    int cbase = (blockIdx.x & 63) * 32;
    int t = threadIdx.x;
    u[t] = U[b*D + t];
    __syncthreads();
    int wave = t >> 6, lane = t & 63;
    float4 uv = *(const float4*)(&u[lane*4]);
    for (int it = 0; it < 8; ++it) {
        int c = cbase + it*4 + wave;
        int id = pred[b*CANDN + c];
        float p;
        if (id == 0) { p = 0.f; }
        else {
            const float* row = item_emb + (size_t)id * D;
            float4 rv = *(const float4*)(row + lane*4);
            p = rv.x*uv.x + rv.y*uv.y + rv.z*uv.z + rv.w*uv.w;
        }
        #pragma unroll
        for (int off = 32; off > 0; off >>= 1) p += __shfl_down(p, off, 64);
        if (lane == 0) out[b*CANDN + c] = p;
    }
}

// ---------------------------------------------------------------------------
extern "C" void kernel_launch(void* const* d_in, const int* in_sizes, int n_in,
                              void* d_out, int out_size, void* d_ws, size_t ws_size,
                              hipStream_t stream)
{
    const float* item_emb = (const float*)d_in[0];
    const float* user_emb = (const float*)d_in[1];
    const float* time_emb = (const float*)d_in[2];
    const float* Wq = (const float*)d_in[3];  const float* bq = (const float*)d_in[4];
    const float* Wk = (const float*)d_in[5];  const float* bk = (const float*)d_in[6];
    const float* Wv = (const float*)d_in[7];  const float* bv = (const float*)d_in[8];
    const float* Wo = (const float*)d_in[9];  const float* bo = (const float*)d_in[10];
    const float* ln1_g = (const float*)d_in[11]; const float* ln1_b = (const float*)d_in[12];
    const float* W1 = (const float*)d_in[13]; const float* b1 = (const float*)d_in[14];
    const float* W2 = (const float*)d_in[15]; const float* b2 = (const float*)d_in[16];
    const float* ln2_g = (const float*)d_in[17]; const float* ln2_b = (const float*)d_in[18];
    const float* fn_g = (const float*)d_in[19]; const float* fn_b = (const float*)d_in[20];
    const float* gWl = (const float*)d_in[21]; const float* gWs = (const float*)d_in[22];
    const float* gWt = (const float*)d_in[23]; const float* gbias = (const float*)d_in[24];
    const int* us   = (const int*)d_in[25];
    const int* sess = (const int*)d_in[26];
    const int* tdlt = (const int*)d_in[27];
    const int* pred = (const int*)d_in[28];
    float* out = (float*)d_out;

    char* ws = (char*)d_ws;
    float* S = (float*)ws;                       ws += (size_t)ROWS*D*4;
    unsigned short* Ybf = (unsigned short*)ws;   ws += (size_t)ROWS*D*2;
    unsigned short* QKVb = (unsigned short*)ws;  // overlay: QKV (12800x768) / H (12800x1024) / LNfin fp32
    unsigned short* Hb = QKVb;
    float* LNf = (float*)QKVb;
    ws += (size_t)ROWS*1024*2;
    unsigned short* WqkvT = (unsigned short*)ws; ws += (size_t)768*256*2;
    unsigned short* WoT   = (unsigned short*)ws; ws += (size_t)256*256*2;
    unsigned short* W1T   = (unsigned short*)ws; ws += (size_t)1024*256*2;
    unsigned short* W2T   = (unsigned short*)ws; ws += (size_t)256*1024*2;
    float* bqkv = (float*)ws;                    ws += 768*4;
    float* u_short = (float*)ws;                 ws += BSZ*D*4;
    float* u_long  = (float*)ws;                 ws += BSZ*D*4;
    float* Ufin    = (float*)ws;                 ws += BSZ*D*4;

    // weight prep
    wtr_k<<<dim3(8,8),   256, 0, stream>>>(Wq, 256, 256,  WqkvT);
    wtr_k<<<dim3(8,8),   256, 0, stream>>>(Wk, 256, 256,  WqkvT + 256*256);
    wtr_k<<<dim3(8,8),   256, 0, stream>>>(Wv, 256, 256,  WqkvT + 512*256);
    wtr_k<<<dim3(8,8),   256, 0, stream>>>(Wo, 256, 256,  WoT);
    wtr_k<<<dim3(32,8),  256, 0, stream>>>(W1, 256, 1024, W1T);
    wtr_k<<<dim3(8,32),  256, 0, stream>>>(W2, 1024, 256, W2T);
    bcat_k<<<1, 256, 0, stream>>>(bq, bk, bv, bqkv);

    // 1. intra-session attention (MFMA)
    intra_k<<<ROWS/4, 256, 0, stream>>>(item_emb, sess, S, u_short);

    // 2. transformer blocks
    for (int blk = 0; blk < 2; ++blk) {
        ln4_k<<<ROWS/4, 256, 0, stream>>>(S, ln1_g, ln1_b, Ybf, nullptr);
        mgemm_k<<<dim3(6,100), 256, 0, stream>>>(Ybf, D, WqkvT, bqkv,
                                                 nullptr, QKVb, 768, 256, 0);
        att_k<<<BSZ*HEADS, 256, 0, stream>>>(QKVb, sess, Ybf);
        mgemm_k<<<dim3(2,100), 256, 0, stream>>>(Ybf, D, WoT, bo,
                                                 S, nullptr, 256, 256, 1);
        ln4_k<<<ROWS/4, 256, 0, stream>>>(S, ln2_g, ln2_b, Ybf, nullptr);
        mgemm_k<<<dim3(8,100), 256, 0, stream>>>(Ybf, D, W1T, b1,
                                                 nullptr, Hb, 1024, 256, 2);
        mgemm_k<<<dim3(2,100), 256, 0, stream>>>(Hb, 1024, W2T, b2,
                                                 S, nullptr, 256, 1024, 1);
    }

    // 3. final LN + u_long
    ln4_k<<<ROWS/4, 256, 0, stream>>>(S, fn_g, fn_b, nullptr, LNf);
    ulong_k<<<BSZ, 256, 0, stream>>>(LNf, user_emb, us, u_long);

    // 4. gate
    gate_k<<<BSZ, 256, 0, stream>>>(u_long, u_short, time_emb, tdlt,
                                    gWl, gWs, gWt, gbias, Ufin);

    // 5. candidate scores
    out_k<<<(BSZ*CANDN)/32, 256, 0, stream>>>(item_emb, pred, Ufin, out);
}

// Round 4
// 870.714 us; speedup vs baseline: 2.1362x; 1.0147x over previous
//
#include <hip/hip_runtime.h>
#include <math.h>

#define D 256
#define HEADS 8
#define DH 32
#define INTER 50
#define INTRA 20
#define BSZ 256
#define CANDN 2048
#define ROWS (BSZ*INTER)   // 12800
#define NITEMS 200000

typedef unsigned short ushort_t;
typedef __attribute__((ext_vector_type(8))) short bf16x8;
typedef __attribute__((ext_vector_type(4))) float f32x4;

__device__ __forceinline__ unsigned short f2b(float f) {
    union { float f; unsigned u; } v; v.f = f;
    unsigned r = v.u + 0x7fffu + ((v.u >> 16) & 1u);
    return (unsigned short)(r >> 16);
}
__device__ __forceinline__ float b2f(unsigned short h) {
    union { unsigned u; float f; } v; v.u = ((unsigned)h) << 16;
    return v.f;
}
__device__ __forceinline__ void gl_lds16(const void* g, void* l) {
    __builtin_amdgcn_global_load_lds(
        (const __attribute__((address_space(1))) unsigned int*)g,
        (__attribute__((address_space(3))) unsigned int*)l, 16, 0, 0);
}

// ============ item_emb fp32 -> bf16 table =================================
__global__ __launch_bounds__(256) void itemb_k(const float* __restrict__ src,
    unsigned short* __restrict__ dst, int n4)
{
    int i = blockIdx.x*256 + threadIdx.x;
    if (i < n4) {
        float4 v = ((const float4*)src)[i];
        ushort4 h; h.x=f2b(v.x); h.y=f2b(v.y); h.z=f2b(v.z); h.w=f2b(v.w);
        ((ushort4*)dst)[i] = h;
    }
}

// ============ intra-session attention via MFMA ============================
// 4 sessions per block, one wave per session. Only 20 real rows in LDS;
// padded fragment rows (20..31) read a shared zero row via address select.
#define XST 264   // bf16 row stride (528B, 16-aligned)
__global__ __launch_bounds__(256) void intra_k(
    const float* __restrict__ item_emb, const unsigned short* __restrict__ item_b,
    const int* __restrict__ sess,
    float* __restrict__ S, float* __restrict__ u_short)
{
    __shared__ __align__(16) unsigned short xb[4][INTRA][XST];
    __shared__ __align__(16) unsigned short zrow[XST];
    __shared__ float sc[4][20][21];
    __shared__ float wsum[4][20];
    __shared__ int ids[4][INTRA];
    int t = threadIdx.x, w = t >> 6, lane = t & 63;
    int s = blockIdx.x*4 + w;                 // session index
    if (lane < INTRA) ids[w][lane] = sess[s*INTRA + lane];
    if (t < 132) ((unsigned int*)zrow)[t] = 0u;
    __syncthreads();
    int col = lane*4;                         // 0..252
    // gather rows (bf16 table if available, else fp32 + convert)
    for (int r = 0; r < INTRA; ++r) {
        int id = ids[w][r];
        ushort4 h;
        if (id == 0) { h.x=h.y=h.z=h.w=0; }
        else if (item_b) {
            h = *(const ushort4*)(item_b + (size_t)id*D + col);
        } else {
            float4 v4 = *(const float4*)(item_emb + (size_t)id*D + col);
            h.x=f2b(v4.x); h.y=f2b(v4.y); h.z=f2b(v4.z); h.w=f2b(v4.w);
        }
        *(ushort4*)&xb[w][r][col] = h;
    }
    __syncthreads();
    // scores = X @ X^T : 2x2 tiles of 16x16, K=256
    int ml = lane & 15, q8 = (lane >> 4) * 8;
    int r1 = 16 + ml;
    f32x4 acc[2][2] = {};
    for (int k0 = 0; k0 < D; k0 += 32) {
        bf16x8 fr0 = *(const bf16x8*)&xb[w][ml][k0 + q8];
        const unsigned short* p1 = (r1 < INTRA) ? &xb[w][r1][k0 + q8] : &zrow[k0 & 0] ;
        bf16x8 fr1 = (r1 < INTRA) ? *(const bf16x8*)&xb[w][r1][k0 + q8]
                                  : *(const bf16x8*)&zrow[q8];
        (void)p1;
        acc[0][0] = __builtin_amdgcn_mfma_f32_16x16x32_bf16(fr0, fr0, acc[0][0], 0,0,0);
        acc[0][1] = __builtin_amdgcn_mfma_f32_16x16x32_bf16(fr0, fr1, acc[0][1], 0,0,0);
        acc[1][0] = __builtin_amdgcn_mfma_f32_16x16x32_bf16(fr1, fr0, acc[1][0], 0,0,0);
        acc[1][1] = __builtin_amdgcn_mfma_f32_16x16x32_bf16(fr1, fr1, acc[1][1], 0,0,0);
    }
    int rb = (lane >> 4) * 4;
    #pragma unroll
    for (int mt = 0; mt < 2; ++mt)
        #pragma unroll
        for (int nt = 0; nt < 2; ++nt)
            #pragma unroll
            for (int i = 0; i < 4; ++i) {
                int row = mt*16 + rb + i, cc = nt*16 + ml;
                if (row < INTRA && cc < INTRA) sc[w][row][cc] = acc[mt][nt][i];
            }
    __syncthreads();
    if (lane < INTRA) {
        float vrow[INTRA]; float mx = -1e30f;
        #pragma unroll
        for (int k = 0; k < INTRA; ++k) {
            float v_ = (ids[w][k] != 0) ? sc[w][lane][k]*(1.0f/16.0f) : -1e9f;
            vrow[k] = v_; mx = fmaxf(mx, v_);
        }
        float ssum = 0.f;
        #pragma unroll
        for (int k = 0; k < INTRA; ++k) { float e_ = expf(vrow[k]-mx); vrow[k]=e_; ssum+=e_; }
        float inv = 1.f/ssum;
        #pragma unroll
        for (int k = 0; k < INTRA; ++k) sc[w][lane][k] = vrow[k]*inv;
    }
    __syncthreads();
    if (lane < INTRA) {
        float s_ = 0.f;
        #pragma unroll
        for (int q = 0; q < INTRA; ++q) s_ += sc[w][q][lane];
        wsum[w][lane] = s_;
    }
    __syncthreads();
    float4 v = {0.f,0.f,0.f,0.f};
    #pragma unroll
    for (int k = 0; k < INTRA; ++k) {
        float ws_ = wsum[w][k];
        ushort4 h = *(const ushort4*)&xb[w][k][col];
        v.x += ws_*b2f(h.x); v.y += ws_*b2f(h.y);
        v.z += ws_*b2f(h.z); v.w += ws_*b2f(h.w);
    }
    int b = s / INTER, srow = s % INTER;
    if (srow == INTER-1) *(float4*)(u_short + (size_t)b*D + col) = v;
    const float kc = -9.210340371976184f / 256.0f;
    float div0 = expf((float)col * kc);
    float div2 = expf((float)(col+2) * kc);
    float4 o;
    o.x = v.x + sinf((float)srow * div0);
    o.y = v.y + cosf((float)srow * div0);
    o.z = v.z + sinf((float)srow * div2);
    o.w = v.w + cosf((float)srow * div2);
    *(float4*)(S + (size_t)s*D + col) = o;
}

// ============ layernorm (ddof=1): wave per row, shuffle-only ==============
__global__ __launch_bounds__(256) void ln4_k(const float* __restrict__ X,
    const float* __restrict__ g, const float* __restrict__ bb,
    unsigned short* __restrict__ Yb, float* __restrict__ Yf)
{
    int w = threadIdx.x >> 6, lane = threadIdx.x & 63;
    size_t row = (size_t)blockIdx.x*4 + w;
    int col = lane*4;
    float4 x = *(const float4*)(X + row*D + col);
    float s_ = x.x + x.y + x.z + x.w;
    #pragma unroll
    for (int off = 32; off > 0; off >>= 1) s_ += __shfl_xor(s_, off, 64);
    float mean = s_ * (1.f/256.f);
    float4 d0; d0.x = x.x-mean; d0.y = x.y-mean; d0.z = x.z-mean; d0.w = x.w-mean;
    float q_ = d0.x*d0.x + d0.y*d0.y + d0.z*d0.z + d0.w*d0.w;
    #pragma unroll
    for (int off = 32; off > 0; off >>= 1) q_ += __shfl_xor(q_, off, 64);
    float inv = 1.f/(sqrtf(q_ * (1.f/255.f)) + 1e-6f);
    float4 g4 = *(const float4*)(g + col), b4 = *(const float4*)(bb + col);
    float4 y;
    y.x = g4.x*d0.x*inv + b4.x; y.y = g4.y*d0.y*inv + b4.y;
    y.z = g4.z*d0.z*inv + b4.z; y.w = g4.w*d0.w*inv + b4.w;
    if (Yb) {
        ushort4 h; h.x=f2b(y.x); h.y=f2b(y.y); h.z=f2b(y.z); h.w=f2b(y.w);
        *(ushort4*)(Yb + row*D + col) = h;
    } else {
        *(float4*)(Yf + row*D + col) = y;
    }
}

// ============ bf16 MFMA GEMM: 128x128 tile, BK=64 (two 32-sub-buffers) ====
#define TM 128
#define TN 128
__global__ __launch_bounds__(256) void mgemm_k(
    const unsigned short* __restrict__ A, int lda,
    const unsigned short* __restrict__ BT,
    const float* __restrict__ bias,
    float* __restrict__ Cf, unsigned short* __restrict__ Cb,
    int ldc, int K, int flags)   // bit0: fp32 accum into Cf, bit1: relu
{
    __shared__ __align__(16) unsigned short As[2][TM*32];
    __shared__ __align__(16) unsigned short Bs[2][TN*32];
    int tid = threadIdx.x;
    int lane = tid & 63, w = tid >> 6;
    int wrow = (w >> 1) * 64, wcol = (w & 1) * 64;
    int tile_m = blockIdx.y * TM, tile_n = blockIdx.x * TN;
    f32x4 acc[4][4] = {};
    const int r_in_chunk = lane >> 2;
    const int e_in_row = (lane & 3) * 8;   // elems (16B)
    const int qoff = (lane >> 4) * 8;
    const int ml = lane & 15;
    for (int k0 = 0; k0 < K; k0 += 64) {
        #pragma unroll
        for (int h = 0; h < 2; ++h) {
            #pragma unroll
            for (int i = 0; i < 2; ++i) {
                int c = w*2 + i;
                int row = c*16 + r_in_chunk;
                gl_lds16(A + (size_t)(tile_m + row)*lda + k0 + h*32 + e_in_row,
                         (char*)As[h] + c*1024 + lane*16);
            }
            #pragma unroll
            for (int i = 0; i < 2; ++i) {
                int c = w*2 + i;
                int row = c*16 + r_in_chunk;
                gl_lds16(BT + (size_t)(tile_n + row)*K + k0 + h*32 + e_in_row,
                         (char*)Bs[h] + c*1024 + lane*16);
            }
        }
        __syncthreads();
        #pragma unroll
        for (int h = 0; h < 2; ++h) {
            bf16x8 af[4], bfr[4];
            #pragma unroll
            for (int mt = 0; mt < 4; ++mt)
                af[mt] = *(const bf16x8*)(As[h] + (wrow + mt*16 + ml)*32 + qoff);
            #pragma unroll
            for (int nt = 0; nt < 4; ++nt)
                bfr[nt] = *(const bf16x8*)(Bs[h] + (wcol + nt*16 + ml)*32 + qoff);
            #pragma unroll
            for (int mt = 0; mt < 4; ++mt)
                #pragma unroll
                for (int nt = 0; nt < 4; ++nt)
                    acc[mt][nt] = __builtin_amdgcn_mfma_f32_16x16x32_bf16(
                        af[mt], bfr[nt], acc[mt][nt], 0, 0, 0);
        }
        __syncthreads();
    }
    int col_l = lane & 15, rbase = (lane >> 4) * 4;
    #pragma unroll
    for (int mt = 0; mt < 4; ++mt) {
        #pragma unroll
        for (int nt = 0; nt < 4; ++nt) {
            int col = tile_n + wcol + nt*16 + col_l;
            float bs = bias ? bias[col] : 0.f;
            #pragma unroll
            for (int i = 0; i < 4; ++i) {
                size_t row = tile_m + wrow + mt*16 + rbase + i;
                float v_ = acc[mt][nt][i] + bs;
                if (flags & 2) v_ = fmaxf(v_, 0.f);
                if (flags & 1) Cf[row*ldc + col] += v_;
                else           Cb[row*ldc + col] = f2b(v_);
            }
        }
    }
}

// ============ weight transpose + fp32->bf16 ===============================
__global__ __launch_bounds__(256) void wtr_k(const float* __restrict__ W,
    int K, int N, unsigned short* __restrict__ WT)
{
    __shared__ float tile[32][33];
    int n0 = blockIdx.x*32, k0 = blockIdx.y*32;
    int tx = threadIdx.x & 31, ty = threadIdx.x >> 5;
    for (int i = ty; i < 32; i += 8)
        tile[i][tx] = W[(size_t)(k0+i)*N + n0 + tx];
    __syncthreads();
    for (int i = ty; i < 32; i += 8)
        WT[(size_t)(n0+i)*K + k0 + tx] = f2b(tile[tx][i]);
}

__global__ void bcat_k(const float* __restrict__ bq, const float* __restrict__ bk,
                       const float* __restrict__ bv, float* __restrict__ o)
{
    int t = threadIdx.x;
    o[t] = bq[t]; o[256+t] = bk[t]; o[512+t] = bv[t];
}

// ============ inter-session MHA via MFMA: block per (b,h) =================
#define AST 40
#define PST 72
__global__ __launch_bounds__(256) void att_k(
    const unsigned short* __restrict__ QKV, const int* __restrict__ sess,
    unsigned short* __restrict__ O)
{
    __shared__ __align__(16) unsigned short qs[64][AST];
    __shared__ __align__(16) unsigned short ks[64][AST];
    __shared__ __align__(16) unsigned short vst[32][PST];
    __shared__ __align__(16) unsigned short pb[64][PST];
    __shared__ float p[50][52];
    __shared__ float msk[52];
    int b = blockIdx.x >> 3, h = blockIdx.x & 7;
    int t = threadIdx.x, w = t >> 6, lane = t & 63;
    for (int u = t; u < 400; u += 256) {
        int arr = u / 200, rem = u % 200, row = rem >> 2, part = rem & 3;
        const unsigned short* src = QKV + ((size_t)(b*INTER+row))*768 + arr*256 + h*32 + part*8;
        ushort4 a = *(const ushort4*)src, c = *(const ushort4*)(src+4);
        unsigned short* dst = (arr ? ks[row] : qs[row]) + part*8;
        *(ushort4*)dst = a; *(ushort4*)(dst+4) = c;
    }
    for (int u = t; u < INTER*32; u += 256) {
        int row = u >> 5, e = u & 31;
        vst[e][row] = QKV[((size_t)(b*INTER+row))*768 + 512 + h*32 + e];
    }
    for (int u = t; u < 32*14; u += 256) {
        int e = u / 14, k = 50 + (u % 14);
        vst[e][k] = 0;
    }
    for (int u = t; u < 64*14; u += 256) {
        int r = u / 14, k = 50 + (u % 14);
        pb[r][k] = 0;
    }
    if (t < INTER) msk[t] = (sess[(b*INTER + t)*INTRA] != 0) ? 1.f : 0.f;
    __syncthreads();
    int ml = lane & 15, q8 = (lane >> 4) * 8, rb = (lane >> 4) * 4;
    {
        bf16x8 afq = *(const bf16x8*)&qs[w*16 + ml][q8];
        #pragma unroll
        for (int nt = 0; nt < 4; ++nt) {
            bf16x8 bfk = *(const bf16x8*)&ks[nt*16 + ml][q8];
            f32x4 a0 = {};
            a0 = __builtin_amdgcn_mfma_f32_16x16x32_bf16(afq, bfk, a0, 0, 0, 0);
            #pragma unroll
            for (int i = 0; i < 4; ++i) {
                int row = w*16 + rb + i, cc = nt*16 + ml;
                if (row < INTER && cc < INTER)
                    p[row][cc] = (msk[cc] != 0.f) ? a0[i]*0.17677669529663687f : -1e9f;
            }
        }
    }
    __syncthreads();
    // softmax: wave w handles rows 13w..13w+12, lane-parallel across row
    {
        int r0 = w*13, r1 = r0+13; if (r1 > INTER) r1 = INTER;
        for (int r = r0; r < r1; ++r) {
            float v = (lane < INTER) ? p[r][lane] : -1e30f;
            float m = v;
            #pragma unroll
            for (int off = 32; off > 0; off >>= 1) m = fmaxf(m, __shfl_xor(m, off, 64));
            float e_ = (lane < INTER) ? expf(v - m) : 0.f;
            float ssum = e_;
            #pragma unroll
            for (int off = 32; off > 0; off >>= 1) ssum += __shfl_xor(ssum, off, 64);
            if (lane < INTER) pb[r][lane] = f2b(e_ / ssum);
        }
    }
    __syncthreads();
    f32x4 acco[2] = {};
    #pragma unroll
    for (int kt = 0; kt < 2; ++kt) {
        bf16x8 ap = *(const bf16x8*)&pb[w*16 + ml][kt*32 + q8];
        #pragma unroll
        for (int nt = 0; nt < 2; ++nt) {
            bf16x8 bv = *(const bf16x8*)&vst[nt*16 + ml][kt*32 + q8];
            acco[nt] = __builtin_amdgcn_mfma_f32_16x16x32_bf16(ap, bv, acco[nt], 0, 0, 0);
        }
    }
    #pragma unroll
    for (int nt = 0; nt < 2; ++nt)
        #pragma unroll
        for (int i = 0; i < 4; ++i) {
            int row = w*16 + rb + i, cc = nt*16 + ml;
            if (row < INTER)
                O[((size_t)(b*INTER+row))*D + h*DH + cc] = f2b(acco[nt][i]);
        }
}

// ============ u_long = sum_l LN_fn(S) + user_emb ==========================
__global__ __launch_bounds__(256) void ulong_k(const float* __restrict__ S1,
    const float* __restrict__ user_emb, const int* __restrict__ us,
    float* __restrict__ u_long)
{
    int b = blockIdx.x, t = threadIdx.x;
    float s = 0.f;
    #pragma unroll 10
    for (int l = 0; l < INTER; ++l) s += S1[((size_t)(b*INTER+l))*D + t];
    int id = us[b];
    float ue = (id == 0) ? 0.f : user_emb[(size_t)id*D + t];
    u_long[b*D + t] = s + ue;
}

// ============ gate + fused user repr ======================================
__global__ __launch_bounds__(256) void gate_k(
    const float* __restrict__ u_long, const float* __restrict__ u_short,
    const float* __restrict__ time_emb, const int* __restrict__ tdlt,
    const float* __restrict__ Wl, const float* __restrict__ Ws,
    const float* __restrict__ Wt, const float* __restrict__ gb,
    float* __restrict__ U)
{
    __shared__ float ul[D], ush[D], te[D];
    int b = blockIdx.x, t = threadIdx.x;
    ul[t]  = u_long[b*D + t];
    ush[t] = u_short[b*D + t];
    te[t]  = time_emb[(size_t)tdlt[b]*D + t];
    __syncthreads();
    float acc = gb[t];
    for (int k = 0; k < D; ++k)
        acc += ul[k]*Wl[k*D + t] + ush[k]*Ws[k*D + t] + te[k]*Wt[k*D + t];
    float tg = 1.f/(1.f + expf(-acc));
    U[b*D + t] = tg*ush[t] + (1.f - tg)*ul[t];
}

// ============ candidate scoring ===========================================
// bf16 path: half-wave (32 lanes x 8 elems) per candidate.
__global__ __launch_bounds__(256) void out_k(
    const float* __restrict__ item_emb, const unsigned short* __restrict__ item_b,
    const int* __restrict__ pred,
    const float* __restrict__ U, float* __restrict__ out)
{
    int b = blockIdx.x >> 6;
    int cbase = (blockIdx.x & 63) * 32;
    int t = threadIdx.x, w = t >> 6, lane = t & 63;
    int hl = lane & 31, half = lane >> 5;
    float4 u0 = *(const float4*)(U + (size_t)b*D + hl*8);
    float4 u1 = *(const float4*)(U + (size_t)b*D + hl*8 + 4);
    for (int it = 0; it < 4; ++it) {
        int c = cbase + it*8 + w*2 + half;
        int id = pred[b*CANDN + c];
        float p = 0.f;
        if (id) {
            if (item_b) {
                const unsigned short* row = item_b + (size_t)id*D + hl*8;
                ushort4 a = *(const ushort4*)row;
                ushort4 d = *(const ushort4*)(row+4);
                p = b2f(a.x)*u0.x + b2f(a.y)*u0.y + b2f(a.z)*u0.z + b2f(a.w)*u0.w
                  + b2f(d.x)*u1.x + b2f(d.y)*u1.y + b2f(d.z)*u1.z + b2f(d.w)*u1.w;
            } else {
                const float* row = item_emb + (size_t)id*D + hl*8;
                float4 a = *(const float4*)row;
                float4 d = *(const float4*)(row+4);
                p = a.x*u0.x + a.y*u0.y + a.z*u0.z + a.w*u0.w
                  + d.x*u1.x + d.y*u1.y + d.z*u1.z + d.w*u1.w;
            }
        }
        #pragma unroll
        for (int off = 16; off > 0; off >>= 1) p += __shfl_xor(p, off, 64);
        if (hl == 0) out[b*CANDN + c] = p;
    }
}

// ---------------------------------------------------------------------------
extern "C" void kernel_launch(void* const* d_in, const int* in_sizes, int n_in,
                              void* d_out, int out_size, void* d_ws, size_t ws_size,
                              hipStream_t stream)
{
    const float* item_emb = (const float*)d_in[0];
    const float* user_emb = (const float*)d_in[1];
    const float* time_emb = (const float*)d_in[2];
    const float* Wq = (const float*)d_in[3];  const float* bq = (const float*)d_in[4];
    const float* Wk = (const float*)d_in[5];  const float* bk = (const float*)d_in[6];
    const float* Wv = (const float*)d_in[7];  const float* bv = (const float*)d_in[8];
    const float* Wo = (const float*)d_in[9];  const float* bo = (const float*)d_in[10];
    const float* ln1_g = (const float*)d_in[11]; const float* ln1_b = (const float*)d_in[12];
    const float* W1 = (const float*)d_in[13]; const float* b1 = (const float*)d_in[14];
    const float* W2 = (const float*)d_in[15]; const float* b2 = (const float*)d_in[16];
    const float* ln2_g = (const float*)d_in[17]; const float* ln2_b = (const float*)d_in[18];
    const float* fn_g = (const float*)d_in[19]; const float* fn_b = (const float*)d_in[20];
    const float* gWl = (const float*)d_in[21]; const float* gWs = (const float*)d_in[22];
    const float* gWt = (const float*)d_in[23]; const float* gbias = (const float*)d_in[24];
    const int* us   = (const int*)d_in[25];
    const int* sess = (const int*)d_in[26];
    const int* tdlt = (const int*)d_in[27];
    const int* pred = (const int*)d_in[28];
    float* out = (float*)d_out;

    char* base = (char*)d_ws;
    size_t off = 0;
    float* S = (float*)(base+off);              off += (size_t)ROWS*D*4;
    unsigned short* Ybf = (unsigned short*)(base+off); off += (size_t)ROWS*D*2;
    unsigned short* QKVb = (unsigned short*)(base+off);
    unsigned short* Hb = QKVb;
    float* LNf = (float*)QKVb;
    off += (size_t)ROWS*1024*2;
    unsigned short* WqkvT = (unsigned short*)(base+off); off += (size_t)768*256*2;
    unsigned short* WoT   = (unsigned short*)(base+off); off += (size_t)256*256*2;
    unsigned short* W1T   = (unsigned short*)(base+off); off += (size_t)1024*256*2;
    unsigned short* W2T   = (unsigned short*)(base+off); off += (size_t)256*1024*2;
    float* bqkv = (float*)(base+off);            off += 768*4;
    float* u_short = (float*)(base+off);         off += BSZ*D*4;
    float* u_long  = (float*)(base+off);         off += BSZ*D*4;
    float* Ufin    = (float*)(base+off);         off += BSZ*D*4;
    // optional bf16 item table (102.4 MB)
    unsigned short* item_b = (unsigned short*)(base+off);
    size_t item_b_bytes = (size_t)NITEMS*D*2;
    bool use_b16 = (off + item_b_bytes) <= ws_size;
    if (!use_b16) item_b = nullptr;

    // weight prep
    wtr_k<<<dim3(8,8),   256, 0, stream>>>(Wq, 256, 256,  WqkvT);
    wtr_k<<<dim3(8,8),   256, 0, stream>>>(Wk, 256, 256,  WqkvT + 256*256);
    wtr_k<<<dim3(8,8),   256, 0, stream>>>(Wv, 256, 256,  WqkvT + 512*256);
    wtr_k<<<dim3(8,8),   256, 0, stream>>>(Wo, 256, 256,  WoT);
    wtr_k<<<dim3(32,8),  256, 0, stream>>>(W1, 256, 1024, W1T);
    wtr_k<<<dim3(8,32),  256, 0, stream>>>(W2, 1024, 256, W2T);
    bcat_k<<<1, 256, 0, stream>>>(bq, bk, bv, bqkv);
    if (use_b16)
        itemb_k<<<(NITEMS*D/4 + 255)/256, 256, 0, stream>>>(item_emb, item_b, NITEMS*D/4);

    // 1. intra-session attention (MFMA)
    intra_k<<<ROWS/4, 256, 0, stream>>>(item_emb, item_b, sess, S, u_short);

    // 2. transformer blocks
    for (int blk = 0; blk < 2; ++blk) {
        ln4_k<<<ROWS/4, 256, 0, stream>>>(S, ln1_g, ln1_b, Ybf, nullptr);
        mgemm_k<<<dim3(6,100), 256, 0, stream>>>(Ybf, D, WqkvT, bqkv,
                                                 nullptr, QKVb, 768, 256, 0);
        att_k<<<BSZ*HEADS, 256, 0, stream>>>(QKVb, sess, Ybf);
        mgemm_k<<<dim3(2,100), 256, 0, stream>>>(Ybf, D, WoT, bo,
                                                 S, nullptr, 256, 256, 1);
        ln4_k<<<ROWS/4, 256, 0, stream>>>(S, ln2_g, ln2_b, Ybf, nullptr);
        mgemm_k<<<dim3(8,100), 256, 0, stream>>>(Ybf, D, W1T, b1,
                                                 nullptr, Hb, 1024, 256, 2);
        mgemm_k<<<dim3(2,100), 256, 0, stream>>>(Hb, 1024, W2T, b2,
                                                 S, nullptr, 256, 1024, 1);
    }

    // 3. final LN + u_long
    ln4_k<<<ROWS/4, 256, 0, stream>>>(S, fn_g, fn_b, nullptr, LNf);
    ulong_k<<<BSZ, 256, 0, stream>>>(LNf, user_emb, us, u_long);

    // 4. gate
    gate_k<<<BSZ, 256, 0, stream>>>(u_long, u_short, time_emb, tdlt,
                                    gWl, gWs, gWt, gbias, Ufin);

    // 5. candidate scores
    out_k<<<(BSZ*CANDN)/32, 256, 0, stream>>>(item_emb, item_b, pred, Ufin, out);
}